// Round 3
// baseline (1677.304 us; speedup 1.0000x reference)
//
#include <hip/hip_runtime.h>

typedef _Float16 f16;
typedef _Float16 f16x8 __attribute__((ext_vector_type(8)));
typedef _Float16 f16x4 __attribute__((ext_vector_type(4)));
typedef float f32x4 __attribute__((ext_vector_type(4)));

#define NB 32
#define NS 1024
#define NI 128
#define NR 1024
#define NO 128
#define NG 16      // workgroups per chunk
#define NC 16      // chunks
#define WARM 32    // warmup steps (typical contraction ~0.6/step -> ~1e-7 residual)
#define CHUNK 64   // real steps per chunk

#define MFMA16(a,b,c) __builtin_amdgcn_mfma_f32_16x16x32_f16((a),(b),(c),0,0,0)

__device__ inline f16x8 cvt8(const float* p) {
  float4 a = *(const float4*)p, b = *(const float4*)(p + 4);
  f16x8 v;
  v[0]=(f16)a.x; v[1]=(f16)a.y; v[2]=(f16)a.z; v[3]=(f16)a.w;
  v[4]=(f16)b.x; v[5]=(f16)b.y; v[6]=(f16)b.z; v[7]=(f16)b.w;
  return v;
}

// ---------------- kernel 1: x_proj[t] in MFMA C-frag lane order ----------------
// slot: xpw[(((t*16 + g)*4 + wv)*64 + lane)*8 + (nt*4 + rg)]
__global__ __launch_bounds__(256) void xp_kernel(
    const float* __restrict__ x, const float* __restrict__ Win, f16* __restrict__ xpw)
{
  __shared__ __attribute__((aligned(16))) f16 Xs[4][32][136];  // 34.8 KB
  const int tid = threadIdx.x, lane = tid & 63, wv = tid >> 6;
  const int q = lane >> 4, ln = lane & 15, mh = wv & 1, nh = wv >> 1;
  const int t0 = blockIdx.x * 4;
#pragma unroll
  for (int j = 0; j < 16; ++j) {
    int idx = tid + j*256;
    int tp = idx >> 10, rem = idx & 1023, b = rem >> 5, f4 = rem & 31;
    float4 v = *(const float4*)(x + ((size_t)b*NS + (t0+tp))*NI + f4*4);
    f16x4 h; h[0]=(f16)v.x; h[1]=(f16)v.y; h[2]=(f16)v.z; h[3]=(f16)v.w;
    *(f16x4*)&Xs[tp][b][f4*4] = h;
  }
  __syncthreads();
  for (int g = 0; g < 16; ++g) {
    f16x8 wIn[2][4];
#pragma unroll
    for (int nt = 0; nt < 2; ++nt) {
      const float* wr = Win + (size_t)(g*64 + nh*32 + nt*16 + ln) * NI;
#pragma unroll
      for (int kt = 0; kt < 4; ++kt) wIn[nt][kt] = cvt8(wr + kt*32 + q*8);
    }
    for (int tp = 0; tp < 4; ++tp) {
      f32x4 a0 = {0,0,0,0}, a1 = {0,0,0,0};
#pragma unroll
      for (int kt = 0; kt < 4; ++kt) {
        f16x8 a = *(const f16x8*)&Xs[tp][mh*16 + ln][kt*32 + q*8];
        a0 = MFMA16(a, wIn[0][kt], a0);
        a1 = MFMA16(a, wIn[1][kt], a1);
      }
      f16x8 o8;
#pragma unroll
      for (int rg = 0; rg < 4; ++rg) { o8[rg] = (f16)a0[rg]; o8[4+rg] = (f16)a1[rg]; }
      *(f16x8*)&xpw[((((size_t)(t0+tp)*16 + g)*4 + wv)*64 + lane)*8] = o8;
    }
  }
}

// ---------------- kernel 2: the recurrence (plain launch, 256 WGs, 1/CU) ----------------
__global__ __launch_bounds__(256, 1) void esn_kernel(
    const float* __restrict__ W, const float* __restrict__ Wow,
    const float* __restrict__ Wob, float* __restrict__ out,
    const f16* __restrict__ xpw, f16* __restrict__ hbuf, int* __restrict__ flags)
{
  // exactly 64 KiB LDS: h[32][1024] f16, XOR-swizzled 16B chunks (chunk ^= row&7)
  __shared__ __attribute__((aligned(16))) f16 Hs[NB][NR];

  const int tid  = threadIdx.x;
  const int lane = tid & 63;
  const int wv   = tid >> 6;   // 0..3
  const int mh   = wv & 1;     // batch-half for recurrence
  const int nh   = wv >> 1;    // n-half (which 32 of the WG's 64 rows)
  const int q    = lane >> 4;
  const int ln   = lane & 15;
  const int sw   = ln & 7;     // LDS chunk swizzle key

  // same-chunk WGs share bx&7 -> same XCD (perf heuristic only)
  const int bx = blockIdx.x;
  const int c  = (bx & 7) * 2 + ((bx >> 3) & 1);
  const int g  = bx >> 4;

  const int warm = (c == 0) ? 0 : WARM;
  const int L    = CHUNK + warm;
  const int t0   = c * CHUNK - warm;

  // ---- W slice as MFMA B-fragments in registers (256 VGPR) ----
  f16x8 wB[2][32];
#pragma unroll
  for (int nt = 0; nt < 2; ++nt) {
    const float* wr = W + (size_t)(g*64 + nh*32 + nt*16 + ln) * NR;
#pragma unroll
    for (int kt = 0; kt < 32; ++kt) wB[nt][kt] = cvt8(wr + kt*32 + q*8);
  }
  // ---- W_out B-fragments in registers (128 VGPR), used by waves 0/1 ----
  f16x8 wO[32];
  if (wv < 2 && ln < 8) {
    const float* wr = Wow + (size_t)(g*8 + ln) * NR;
#pragma unroll
    for (int kt = 0; kt < 32; ++kt) wO[kt] = cvt8(wr + kt*32 + q*8);
  } else {
#pragma unroll
    for (int kt = 0; kt < 32; ++kt) wO[kt] = (f16x8){};
  }
  const float bz = Wob[g*8 + (ln & 7)];

  // h(-1) = 0
#pragma unroll
  for (int j = 0; j < 16; ++j) *(((f16x8*)&Hs[0][0]) + tid + j*256) = (f16x8){};

  f16x8 xp_cur = *(const f16x8*)&xpw[((((size_t)t0*16 + g)*4 + wv)*64 + lane)*8];
  __syncthreads();

  // readout y(tg): waves 0/1, batch-half = wv, full K
  auto do_y = [&](int tg) {
    const int arow = wv*16 + ln;
    f32x4 y0 = {0,0,0,0}, y1 = {0,0,0,0};
#pragma unroll
    for (int kt = 0; kt < 32; ++kt) {
      f16x8 a = *(const f16x8*)&Hs[arow][((kt*4 + q) ^ sw) * 8];
      if (kt & 1) y1 = MFMA16(a, wO[kt], y1);
      else        y0 = MFMA16(a, wO[kt], y0);
    }
    f32x4 y = y0 + y1;
    if (ln < 8) {
#pragma unroll
      for (int rg = 0; rg < 4; ++rg)
        out[(size_t)(wv*16 + q*4 + rg)*(NS*NO) + (size_t)tg*NO + g*8 + ln] = y[rg] + bz;
    }
  };

  for (int s = 0; s < L; ++s) {
    const int t  = t0 + s;
    const int pb = s & 1;
    f16x8 xp_next = (f16x8){};
    if (s + 1 < L)
      xp_next = *(const f16x8*)&xpw[((((size_t)(t+1)*16 + g)*4 + wv)*64 + lane)*8];

    // acc = x_proj(t) + h(s-1) @ W_slice^T   (4 chains)
    f32x4 a00 = {(float)xp_cur[0], (float)xp_cur[1], (float)xp_cur[2], (float)xp_cur[3]};
    f32x4 a10 = {(float)xp_cur[4], (float)xp_cur[5], (float)xp_cur[6], (float)xp_cur[7]};
    f32x4 a01 = {0,0,0,0}, a11 = {0,0,0,0};
    const int arow = mh*16 + ln;
#pragma unroll
    for (int kt = 0; kt < 32; ++kt) {
      f16x8 a = *(const f16x8*)&Hs[arow][((kt*4 + q) ^ sw) * 8];
      if (kt & 1) { a01 = MFMA16(a, wB[0][kt], a01); a11 = MFMA16(a, wB[1][kt], a11); }
      else        { a00 = MFMA16(a, wB[0][kt], a00); a10 = MFMA16(a, wB[1][kt], a10); }
    }
    f32x4 accN0 = a00 + a01;
    f32x4 accN1 = a10 + a11;

    // tanh + publish own [32 x 64] slice
    f16* hb = hbuf + (size_t)(c*2 + pb)*NB*NR;
    const int r0 = g*64 + nh*32 + ln;
#pragma unroll
    for (int nt = 0; nt < 2; ++nt) {
      f32x4 av = nt ? accN1 : accN0;
#pragma unroll
      for (int rg = 0; rg < 4; ++rg) {
        float e  = __expf(2.f * av[rg]);
        float hv = 1.f - 2.f * __builtin_amdgcn_rcpf(e + 1.f);
        hb[(mh*16 + q*4 + rg)*NR + r0 + nt*16] = (f16)hv;
      }
    }
    __syncthreads();  // drain stores before flag
    if (tid == 0)
      __hip_atomic_store(&flags[(c*NG + g)*16], s + 1, __ATOMIC_RELEASE, __HIP_MEMORY_SCOPE_AGENT);

    // overlap: waves 0/1 readout of previous step; wave 3 spins for peers
    if (wv < 2) {
      if (s > warm) do_y(t - 1);
    } else if (wv == 3) {
      if (lane < 16) {
        const int* fp = &flags[(c*NG + lane)*16];
        // watchdog: convert a co-residency violation into wrong-answer, not hang
        long long dl = clock64() + 10000000LL;  // ~4 ms
        while (__hip_atomic_load(fp, __ATOMIC_RELAXED, __HIP_MEMORY_SCOPE_AGENT) < s + 1) {
          if (clock64() > dl) break;
        }
      }
      __threadfence();  // acquire
    }
    __syncthreads();

    // gather full h(s) -> LDS (swizzled)
#pragma unroll
    for (int j = 0; j < 16; ++j) {
      int idx = tid + j*256;
      int b = idx >> 7, ck = idx & 127;
      f16x8 v = *(const f16x8*)&hb[b*NR + ck*8];
      *(f16x8*)&Hs[b][((ck ^ (b & 7)) * 8)] = v;
    }
    xp_cur = xp_next;
    __syncthreads();
  }
  if (wv < 2) do_y(t0 + L - 1);
}

extern "C" void kernel_launch(void* const* d_in, const int* in_sizes, int n_in,
                              void* d_out, int out_size, void* d_ws, size_t ws_size,
                              hipStream_t stream) {
  (void)in_sizes; (void)n_in; (void)out_size; (void)ws_size;
  const float* x   = (const float*)d_in[0];
  const float* Win = (const float*)d_in[1];
  const float* W   = (const float*)d_in[2];
  const float* Wow = (const float*)d_in[3];
  const float* Wob = (const float*)d_in[4];
  float* out = (float*)d_out;

  f16* xpw   = (f16*)d_ws;                                         // 64 MB
  f16* hbuf  = (f16*)((char*)d_ws + (size_t)NS*NB*NR*sizeof(f16)); // 2 MB
  int* flags = (int*)((char*)hbuf + (size_t)NC*2*NB*NR*sizeof(f16));

  hipMemsetAsync(flags, 0, NC*NG*16*sizeof(int), stream);

  xp_kernel<<<dim3(NS/4), dim3(256), 0, stream>>>(x, Win, xpw);
  esn_kernel<<<dim3(256), dim3(256), 0, stream>>>(W, Wow, Wob, out, xpw, hbuf, flags);
}

// Round 4
// 662.384 us; speedup vs baseline: 2.5322x; 2.5322x over previous
//
#include <hip/hip_runtime.h>

typedef _Float16 f16;
typedef _Float16 f16x8 __attribute__((ext_vector_type(8)));
typedef _Float16 f16x4 __attribute__((ext_vector_type(4)));
typedef float f32x4 __attribute__((ext_vector_type(4)));

#define NB 32
#define NS 1024
#define NI 128
#define NR 1024
#define NO 128
#define NG 16      // workgroups per chunk
#define NC 16      // chunks
#define WARM 32    // warmup steps
#define CHUNK 64   // real steps per chunk

#define MFMA16(a,b,c) __builtin_amdgcn_mfma_f32_16x16x32_f16((a),(b),(c),0,0,0)

__device__ inline f16x8 cvt8(const float* p) {
  float4 a = *(const float4*)p, b = *(const float4*)(p + 4);
  f16x8 v;
  v[0]=(f16)a.x; v[1]=(f16)a.y; v[2]=(f16)a.z; v[3]=(f16)a.w;
  v[4]=(f16)b.x; v[5]=(f16)b.y; v[6]=(f16)b.z; v[7]=(f16)b.w;
  return v;
}

// ---------------- kernel 1: x_proj[t] in MFMA C-frag lane order ----------------
// element (g,wv,lane,nt,rg): b = (wv&1)*16 + (lane>>4)*4 + rg,
//                            r = g*64 + (wv>>1)*32 + 2*(lane&15) + nt
__global__ __launch_bounds__(256) void xp_kernel(
    const float* __restrict__ x, const float* __restrict__ Win, f16* __restrict__ xpw)
{
  __shared__ __attribute__((aligned(16))) f16 Xs[4][32][136];  // 34.8 KB
  const int tid = threadIdx.x, lane = tid & 63, wv = tid >> 6;
  const int q = lane >> 4, ln = lane & 15, mh = wv & 1, nh = wv >> 1;
  const int t0 = blockIdx.x * 4;
#pragma unroll
  for (int j = 0; j < 16; ++j) {
    int idx = tid + j*256;
    int tp = idx >> 10, rem = idx & 1023, b = rem >> 5, f4 = rem & 31;
    float4 v = *(const float4*)(x + ((size_t)b*NS + (t0+tp))*NI + f4*4);
    f16x4 h; h[0]=(f16)v.x; h[1]=(f16)v.y; h[2]=(f16)v.z; h[3]=(f16)v.w;
    *(f16x4*)&Xs[tp][b][f4*4] = h;
  }
  __syncthreads();
  for (int g = 0; g < 16; ++g) {
    f16x8 wIn[2][4];
#pragma unroll
    for (int nt = 0; nt < 2; ++nt) {
      const float* wr = Win + (size_t)(g*64 + nh*32 + 2*ln + nt) * NI;
#pragma unroll
      for (int kt = 0; kt < 4; ++kt) wIn[nt][kt] = cvt8(wr + kt*32 + q*8);
    }
    for (int tp = 0; tp < 4; ++tp) {
      f32x4 a0 = {0,0,0,0}, a1 = {0,0,0,0};
#pragma unroll
      for (int kt = 0; kt < 4; ++kt) {
        f16x8 a = *(const f16x8*)&Xs[tp][mh*16 + ln][kt*32 + q*8];
        a0 = MFMA16(a, wIn[0][kt], a0);
        a1 = MFMA16(a, wIn[1][kt], a1);
      }
      f16x8 o8;
#pragma unroll
      for (int rg = 0; rg < 4; ++rg) { o8[rg] = (f16)a0[rg]; o8[4+rg] = (f16)a1[rg]; }
      *(f16x8*)&xpw[((((size_t)(t0+tp)*16 + g)*4 + wv)*64 + lane)*8] = o8;
    }
  }
}

// ---------------- kernel 2: the recurrence (plain launch, 256 WGs, 1/CU) ----------------
__global__ __launch_bounds__(256, 1) void esn_kernel(
    const float* __restrict__ W, const float* __restrict__ Wow,
    const float* __restrict__ Wob, float* __restrict__ out,
    const f16* __restrict__ xpw, unsigned* __restrict__ hbuf, int* __restrict__ flags)
{
  // 64 KiB LDS: h[32][1024] f16, XOR-swizzled 16B chunks (chunk ^= row&7)
  __shared__ __attribute__((aligned(16))) f16 Hs[NB][NR];

  const int tid  = threadIdx.x;
  const int lane = tid & 63;
  const int wv   = tid >> 6;   // 0..3
  const int mh   = wv & 1;     // batch-half
  const int nh   = wv >> 1;    // n-half
  const int q    = lane >> 4;
  const int ln   = lane & 15;
  const int sw   = ln & 7;     // LDS chunk swizzle key

  const int bx = blockIdx.x;
  const int c  = (bx & 7) * 2 + ((bx >> 3) & 1);  // chunk; 16 WGs share bx%8 -> same XCD
  const int g  = bx >> 4;

  const int warm = (c == 0) ? 0 : WARM;
  const int L    = CHUNK + warm;
  const int t0   = c * CHUNK - warm;

  // ---- W slice as MFMA B-fragments in registers; rows base+2*ln+nt (adjacent pair) ----
  f16x8 wB[2][32];
#pragma unroll
  for (int nt = 0; nt < 2; ++nt) {
    const float* wr = W + (size_t)(g*64 + nh*32 + 2*ln + nt) * NR;
#pragma unroll
    for (int kt = 0; kt < 32; ++kt) wB[nt][kt] = cvt8(wr + kt*32 + q*8);
  }
  // ---- W_out B-fragments (waves 0/1) ----
  f16x8 wO[32];
  if (wv < 2 && ln < 8) {
    const float* wr = Wow + (size_t)(g*8 + ln) * NR;
#pragma unroll
    for (int kt = 0; kt < 32; ++kt) wO[kt] = cvt8(wr + kt*32 + q*8);
  } else {
#pragma unroll
    for (int kt = 0; kt < 32; ++kt) wO[kt] = (f16x8){};
  }
  const float bz = Wob[g*8 + (ln & 7)];

  // h(-1) = 0
#pragma unroll
  for (int j = 0; j < 16; ++j) *(((f16x8*)&Hs[0][0]) + tid + j*256) = (f16x8){};

  f16x8 xp_cur = *(const f16x8*)&xpw[((((size_t)t0*16 + g)*4 + wv)*64 + lane)*8];
  __syncthreads();

  auto do_y = [&](int tg) {
    const int arow = wv*16 + ln;
    f32x4 y0 = {0,0,0,0}, y1 = {0,0,0,0};
#pragma unroll
    for (int kt = 0; kt < 32; ++kt) {
      f16x8 a = *(const f16x8*)&Hs[arow][((kt*4 + q) ^ sw) * 8];
      if (kt & 1) y1 = MFMA16(a, wO[kt], y1);
      else        y0 = MFMA16(a, wO[kt], y0);
    }
    f32x4 y = y0 + y1;
    if (ln < 8) {
#pragma unroll
      for (int rg = 0; rg < 4; ++rg)
        out[(size_t)(wv*16 + q*4 + rg)*(NS*NO) + (size_t)tg*NO + g*8 + ln] = y[rg] + bz;
    }
  };

  const int cb = g*32 + nh*16;  // dword column base within a 512-dword h row

  for (int s = 0; s < L; ++s) {
    const int t  = t0 + s;
    const int pb = s & 1;
    f16x8 xp_next = (f16x8){};
    if (s + 1 < L)
      xp_next = *(const f16x8*)&xpw[((((size_t)(t+1)*16 + g)*4 + wv)*64 + lane)*8];

    // acc = x_proj(t) + h(s-1) @ W_slice^T
    f32x4 a00 = {(float)xp_cur[0], (float)xp_cur[1], (float)xp_cur[2], (float)xp_cur[3]};
    f32x4 a10 = {(float)xp_cur[4], (float)xp_cur[5], (float)xp_cur[6], (float)xp_cur[7]};
    f32x4 a01 = {0,0,0,0}, a11 = {0,0,0,0};
    const int arow = mh*16 + ln;
#pragma unroll
    for (int kt = 0; kt < 32; ++kt) {
      f16x8 a = *(const f16x8*)&Hs[arow][((kt*4 + q) ^ sw) * 8];
      if (kt & 1) { a01 = MFMA16(a, wB[0][kt], a01); a11 = MFMA16(a, wB[1][kt], a11); }
      else        { a00 = MFMA16(a, wB[0][kt], a00); a10 = MFMA16(a, wB[1][kt], a10); }
    }
    f32x4 accN0 = a00 + a01;
    f32x4 accN1 = a10 + a11;

    // tanh + publish as write-through dword atomics (2 f16 per dword, adjacent cols)
    unsigned* hbw = hbuf + (size_t)(c*2 + pb)*NB*512;
#pragma unroll
    for (int rg = 0; rg < 4; ++rg) {
      float e0 = __expf(2.f * accN0[rg]);
      float h0 = 1.f - 2.f * __builtin_amdgcn_rcpf(e0 + 1.f);
      float e1 = __expf(2.f * accN1[rg]);
      float h1 = 1.f - 2.f * __builtin_amdgcn_rcpf(e1 + 1.f);
      f16 v0 = (f16)h0, v1 = (f16)h1;
      unsigned pk = (unsigned)__builtin_bit_cast(unsigned short, v0)
                  | ((unsigned)__builtin_bit_cast(unsigned short, v1) << 16);
      int b = mh*16 + q*4 + rg;
      __hip_atomic_store(&hbw[b*512 + cb + ln], pk, __ATOMIC_RELAXED, __HIP_MEMORY_SCOPE_AGENT);
    }
    __syncthreads();  // drains vmcnt(0) per wave -> publishes globally visible (sc1)
    if (tid == 0)
      __hip_atomic_store(&flags[(c*NG + g)*16], s + 1, __ATOMIC_RELAXED, __HIP_MEMORY_SCOPE_AGENT);

    // overlap: waves 0/1 readout previous step; wave 3 spins for peers (no fences)
    if (wv < 2) {
      if (s > warm) do_y(t - 1);
    } else if (wv == 3) {
      if (lane < 16) {
        const int* fp = &flags[(c*NG + lane)*16];
        long long dl = clock64() + 10000000LL;  // watchdog ~4 ms
        while (__hip_atomic_load(fp, __ATOMIC_RELAXED, __HIP_MEMORY_SCOPE_AGENT) < s + 1) {
          if (clock64() > dl) break;
        }
      }
    }
    __syncthreads();

    // gather full h(s) -> LDS via device-coherent dword loads, pipelined 4x16 depth-2
    {
      unsigned* Hw = (unsigned*)&Hs[0][0];
      unsigned tmp[2][16];
#pragma unroll
      for (int j = 0; j < 16; ++j)
        tmp[0][j] = __hip_atomic_load(&hbw[tid + j*256], __ATOMIC_RELAXED, __HIP_MEMORY_SCOPE_AGENT);
#pragma unroll
      for (int jo = 0; jo < 4; ++jo) {
        if (jo + 1 < 4) {
#pragma unroll
          for (int j = 0; j < 16; ++j)
            tmp[(jo+1)&1][j] = __hip_atomic_load(&hbw[tid + ((jo+1)*16 + j)*256],
                                                 __ATOMIC_RELAXED, __HIP_MEMORY_SCOPE_AGENT);
        }
#pragma unroll
        for (int j = 0; j < 16; ++j) {
          int idx = tid + (jo*16 + j)*256;      // 0..16383 dwords
          int b = idx >> 9, d = idx & 511;
          int ck = d >> 2, e = d & 3;
          Hw[b*512 + ((ck ^ (b & 7)) << 2) + e] = tmp[jo&1][j];
        }
      }
    }
    xp_cur = xp_next;
    __syncthreads();
  }
  if (wv < 2) do_y(t0 + L - 1);
}

extern "C" void kernel_launch(void* const* d_in, const int* in_sizes, int n_in,
                              void* d_out, int out_size, void* d_ws, size_t ws_size,
                              hipStream_t stream) {
  (void)in_sizes; (void)n_in; (void)out_size; (void)ws_size;
  const float* x   = (const float*)d_in[0];
  const float* Win = (const float*)d_in[1];
  const float* W   = (const float*)d_in[2];
  const float* Wow = (const float*)d_in[3];
  const float* Wob = (const float*)d_in[4];
  float* out = (float*)d_out;

  f16*      xpw   = (f16*)d_ws;                                         // 64 MB
  unsigned* hbuf  = (unsigned*)((char*)d_ws + (size_t)NS*NB*NR*sizeof(f16)); // 2 MB
  int*      flags = (int*)((char*)hbuf + (size_t)NC*2*NB*512*sizeof(unsigned));

  hipMemsetAsync(flags, 0, NC*NG*16*sizeof(int), stream);

  xp_kernel<<<dim3(NS/4), dim3(256), 0, stream>>>(x, Win, xpw);
  esn_kernel<<<dim3(256), dim3(256), 0, stream>>>(W, Wow, Wob, out, xpw, hbuf, flags);
}